// Round 1
// baseline (553.497 us; speedup 1.0000x reference)
//
#include <hip/hip_runtime.h>
#include <stdint.h>

#define DM 768
#define VOC 32128
#define NTOK 2048
#define IGN (-100)

typedef __bf16 bf16x8 __attribute__((ext_vector_type(8)));
typedef float f32x4 __attribute__((ext_vector_type(4)));

typedef __attribute__((address_space(1))) void gvoid_t;
typedef __attribute__((address_space(3))) void svoid_t;

__device__ __forceinline__ void gl_lds16(const void* g, void* s) {
  // 16B per lane; LDS dest = wave-uniform base + lane*16
  __builtin_amdgcn_global_load_lds((gvoid_t*)g, (svoid_t*)s, 16, 0, 0);
}

__device__ __forceinline__ unsigned short f2bf(float f) {
  unsigned int u = __float_as_uint(f);
  u = (u + 0x7fffu + ((u >> 16) & 1u)) >> 16;  // RNE
  return (unsigned short)u;
}

// ---------------- W fp32 -> bf16 ----------------
__global__ void __launch_bounds__(256) cvt_w_kernel(const float* __restrict__ W,
                                                    unsigned short* __restrict__ Wb) {
  size_t i = ((size_t)blockIdx.x * 256 + threadIdx.x) * 4;
  float4 v = *(const float4*)(W + i);
  ushort4 o;
  o.x = f2bf(v.x); o.y = f2bf(v.y); o.z = f2bf(v.z); o.w = f2bf(v.w);
  *(ushort4*)(Wb + i) = o;
}

// ---------------- RMSNorm -> bf16 ----------------
__global__ void __launch_bounds__(256) rmsnorm_kernel(const float* __restrict__ x,
                                                      const float* __restrict__ w,
                                                      unsigned short* __restrict__ h) {
  int tok = blockIdx.x;
  const float* xr = x + (size_t)tok * DM;
  int t = threadIdx.x;
  float v0 = xr[t], v1 = xr[t + 256], v2 = xr[t + 512];
  float ss = v0 * v0 + v1 * v1 + v2 * v2;
  for (int off = 32; off; off >>= 1) ss += __shfl_down(ss, off);
  __shared__ float red[4];
  int wv = t >> 6, ln = t & 63;
  if (ln == 0) red[wv] = ss;
  __syncthreads();
  float tot = red[0] + red[1] + red[2] + red[3];
  float inv = rsqrtf(tot * (1.0f / DM) + 1e-6f);
  unsigned short* hr = h + (size_t)tok * DM;
  hr[t]       = f2bf(v0 * inv * w[t]);
  hr[t + 256] = f2bf(v1 * inv * w[t + 256]);
  hr[t + 512] = f2bf(v2 * inv * w[t + 512]);
}

// ---------------- GEMM: C[m][n] = sum_k A[m][k]*B[n][k], bf16 in / f32 out ----
// A: [2048][768] bf16, B: [32128][768] bf16, C: f32 (unaligned base ok, scalar stores)
// Block 256 thr (4 waves), tile 128x128, BK=32, m97-style global_load_lds staging.
__global__ void __launch_bounds__(256, 2) gemm_kernel(const unsigned short* __restrict__ A,
                                                      const unsigned short* __restrict__ Bw,
                                                      float* __restrict__ C) {
  __shared__ __align__(16) unsigned short As[128 * 32];
  __shared__ __align__(16) unsigned short Bs[128 * 32];

  const int m0 = blockIdx.x * 128;   // x fastest => 16 consecutive blocks share B-tile
  const int n0 = blockIdx.y * 128;
  const int tid = threadIdx.x;
  const int wv = tid >> 6, ln = tid & 63;
  const int srow = ln >> 2;          // 0..15
  const int scol = (ln & 3) * 8;     // 0,8,16,24 (bf16 elems; 16B per lane)

  const unsigned short* aSrc0 = A + (size_t)(m0 + wv * 32 + srow) * DM + scol;
  const unsigned short* aSrc1 = aSrc0 + (size_t)16 * DM;
  const unsigned short* bSrc0 = Bw + (size_t)(n0 + wv * 32 + srow) * DM + scol;
  const unsigned short* bSrc1 = bSrc0 + (size_t)16 * DM;
  unsigned short* aDst0 = &As[(wv * 32) * 32];
  unsigned short* aDst1 = &As[(wv * 32 + 16) * 32];
  unsigned short* bDst0 = &Bs[(wv * 32) * 32];
  unsigned short* bDst1 = &Bs[(wv * 32 + 16) * 32];

  const int quad = ln >> 4, l15 = ln & 15;
  const int wr = (wv >> 1) * 64;     // wave M offset in tile
  const int wc = (wv & 1) * 64;      // wave N offset in tile

  f32x4 acc[4][4];
#pragma unroll
  for (int i = 0; i < 4; ++i)
#pragma unroll
    for (int j = 0; j < 4; ++j) {
      acc[i][j][0] = 0.f; acc[i][j][1] = 0.f; acc[i][j][2] = 0.f; acc[i][j][3] = 0.f;
    }

  for (int kt = 0; kt < 24; ++kt) {
    const int ko = kt * 32;
    gl_lds16(aSrc0 + ko, aDst0);
    gl_lds16(aSrc1 + ko, aDst1);
    gl_lds16(bSrc0 + ko, bDst0);
    gl_lds16(bSrc1 + ko, bDst1);
    __syncthreads();

    bf16x8 af[4], bfv[4];
#pragma unroll
    for (int i = 0; i < 4; ++i) {
      af[i]  = *(const bf16x8*)(As + (wr + i * 16 + l15) * 32 + quad * 8);
      bfv[i] = *(const bf16x8*)(Bs + (wc + i * 16 + l15) * 32 + quad * 8);
    }
#pragma unroll
    for (int mi = 0; mi < 4; ++mi)
#pragma unroll
      for (int ni = 0; ni < 4; ++ni)
        acc[mi][ni] = __builtin_amdgcn_mfma_f32_16x16x32_bf16(af[mi], bfv[ni], acc[mi][ni], 0, 0, 0);
    __syncthreads();
  }

  // Epilogue: C/D layout col=lane&15 (N), row=quad*4+reg (M). Scalar f32 stores.
#pragma unroll
  for (int mi = 0; mi < 4; ++mi) {
#pragma unroll
    for (int r = 0; r < 4; ++r) {
      const int row = m0 + wr + mi * 16 + quad * 4 + r;
      float* cp = C + (size_t)row * VOC + (n0 + wc + l15);
#pragma unroll
      for (int ni = 0; ni < 4; ++ni) cp[ni * 16] = acc[mi][ni][r];
    }
  }
}

// ---------------- per-token CE (online logsumexp) ----------------
__global__ void __launch_bounds__(256) loss_kernel(const float* __restrict__ scores,
                                                   const int* __restrict__ labels,
                                                   float* __restrict__ nll) {
  const int tok = blockIdx.x;
  const float* row = scores + (size_t)tok * VOC;
  float m = -1e30f, s = 0.f;
  for (int j = threadIdx.x; j < VOC; j += 256) {
    float v = row[j];
    float nm = fmaxf(m, v);
    s = s * __expf(m - nm) + __expf(v - nm);
    m = nm;
  }
  for (int off = 32; off; off >>= 1) {
    float m2 = __shfl_down(m, off), s2 = __shfl_down(s, off);
    float nm = fmaxf(m, m2);
    s = s * __expf(m - nm) + s2 * __expf(m2 - nm);
    m = nm;
  }
  __shared__ float ms[4], sh[4];
  int wv = threadIdx.x >> 6, ln = threadIdx.x & 63;
  if (ln == 0) { ms[wv] = m; sh[wv] = s; }
  __syncthreads();
  if (threadIdx.x == 0) {
    float M = ms[0], S = sh[0];
    for (int i = 1; i < 4; ++i) {
      float nm = fmaxf(M, ms[i]);
      S = S * __expf(M - nm) + sh[i] * __expf(ms[i] - nm);
      M = nm;
    }
    int lab = labels[tok];
    float v = 0.f;
    if (lab != IGN) v = (M + logf(S)) - row[lab];
    nll[tok] = v;
  }
}

__global__ void __launch_bounds__(256) reduce_kernel(const float* __restrict__ nll,
                                                     const int* __restrict__ labels,
                                                     float* __restrict__ out) {
  float s = 0.f, c = 0.f;
  for (int i = threadIdx.x; i < NTOK; i += 256) {
    s += nll[i];
    c += (labels[i] != IGN) ? 1.0f : 0.0f;
  }
  for (int off = 32; off; off >>= 1) { s += __shfl_down(s, off); c += __shfl_down(c, off); }
  __shared__ float rs[4], rc[4];
  int wv = threadIdx.x >> 6, ln = threadIdx.x & 63;
  if (ln == 0) { rs[wv] = s; rc[wv] = c; }
  __syncthreads();
  if (threadIdx.x == 0) {
    float S = rs[0] + rs[1] + rs[2] + rs[3];
    float Cc = rc[0] + rc[1] + rc[2] + rc[3];
    out[0] = S / fmaxf(Cc, 1.0f);
  }
}

extern "C" void kernel_launch(void* const* d_in, const int* in_sizes, int n_in,
                              void* d_out, int out_size, void* d_ws, size_t ws_size,
                              hipStream_t stream) {
  const float* hs     = (const float*)d_in[0];  // [4,512,768] f32
  const int*   labels = (const int*)d_in[1];    // [4,512] i32
  const float* lnw    = (const float*)d_in[2];  // [768] f32
  const float* W      = (const float*)d_in[3];  // [32128,768] f32

  float* out    = (float*)d_out;
  float* scores = out + 1;                      // [2048,32128] f32 (4B-aligned only)

  unsigned short* Wb = (unsigned short*)d_ws;                                   // 49.3 MB
  unsigned short* Hb = (unsigned short*)((char*)d_ws + (size_t)VOC * DM * 2);   // 3.1 MB
  float* nll         = (float*)((char*)d_ws + (size_t)VOC * DM * 2 + (size_t)NTOK * DM * 2);

  cvt_w_kernel<<<(VOC * DM / 4) / 256, 256, 0, stream>>>(W, Wb);
  rmsnorm_kernel<<<NTOK, 256, 0, stream>>>(hs, lnw, Hb);
  gemm_kernel<<<dim3(NTOK / 128, VOC / 128), 256, 0, stream>>>(Hb, Wb, scores);
  loss_kernel<<<NTOK, 256, 0, stream>>>(scores, labels, nll);
  reduce_kernel<<<1, 256, 0, stream>>>(nll, labels, out);
}

// Round 2
// 474.200 us; speedup vs baseline: 1.1672x; 1.1672x over previous
//
#include <hip/hip_runtime.h>
#include <stdint.h>

#define DM 768
#define VOC 32128
#define NTOK 2048
#define NBY (VOC / 128)   // 251 n-tiles
#define IGN (-100)

typedef __bf16 bf16x8 __attribute__((ext_vector_type(8)));
typedef float f32x4 __attribute__((ext_vector_type(4)));

typedef __attribute__((address_space(1))) void gvoid_t;
typedef __attribute__((address_space(3))) void svoid_t;

__device__ __forceinline__ void gl_lds16(const void* g, void* s) {
  // 16B per lane; LDS dest = wave-uniform base + lane*16
  __builtin_amdgcn_global_load_lds((gvoid_t*)g, (svoid_t*)s, 16, 0, 0);
}

__device__ __forceinline__ unsigned short f2bf(float f) {
  unsigned int u = __float_as_uint(f);
  u = (u + 0x7fffu + ((u >> 16) & 1u)) >> 16;  // RNE
  return (unsigned short)u;
}

// ---------------- W fp32 -> bf16 ----------------
__global__ void __launch_bounds__(256) cvt_w_kernel(const float* __restrict__ W,
                                                    unsigned short* __restrict__ Wb) {
  size_t i = ((size_t)blockIdx.x * 256 + threadIdx.x) * 4;
  float4 v = *(const float4*)(W + i);
  ushort4 o;
  o.x = f2bf(v.x); o.y = f2bf(v.y); o.z = f2bf(v.z); o.w = f2bf(v.w);
  *(ushort4*)(Wb + i) = o;
}

// ---------------- RMSNorm -> bf16 ----------------
__global__ void __launch_bounds__(256) rmsnorm_kernel(const float* __restrict__ x,
                                                      const float* __restrict__ w,
                                                      unsigned short* __restrict__ h) {
  int tok = blockIdx.x;
  const float* xr = x + (size_t)tok * DM;
  int t = threadIdx.x;
  float v0 = xr[t], v1 = xr[t + 256], v2 = xr[t + 512];
  float ss = v0 * v0 + v1 * v1 + v2 * v2;
  for (int off = 32; off; off >>= 1) ss += __shfl_down(ss, off);
  __shared__ float red[4];
  int wv = t >> 6, ln = t & 63;
  if (ln == 0) red[wv] = ss;
  __syncthreads();
  float tot = red[0] + red[1] + red[2] + red[3];
  float inv = rsqrtf(tot * (1.0f / DM) + 1e-6f);
  unsigned short* hr = h + (size_t)tok * DM;
  hr[t]       = f2bf(v0 * inv * w[t]);
  hr[t + 256] = f2bf(v1 * inv * w[t + 256]);
  hr[t + 512] = f2bf(v2 * inv * w[t + 512]);
}

// ---------------- GEMM + fused CE partials ----------------
// C[m][n] = sum_k A[m][k]*B[n][k]; also per-block per-row (max, sumexp) partials.
// LDS K-slot XOR swizzle: elem (row r, slot q) stored at slot q ^ ((r>>1)&3)
// -> quad-group ds_read_b128 spreads over 8 banks (2-way, free per m136),
//    while global_load_lds's linear lane->LDS mapping is preserved.
__global__ void __launch_bounds__(256, 2) gemm_kernel(const unsigned short* __restrict__ A,
                                                      const unsigned short* __restrict__ Bw,
                                                      float* __restrict__ C,
                                                      float* __restrict__ Pm,
                                                      float* __restrict__ Ps) {
  __shared__ __align__(16) unsigned short As[128 * 32];
  __shared__ __align__(16) unsigned short Bs[128 * 32];

  const int m0 = blockIdx.x * 128;
  const int n0 = blockIdx.y * 128;
  const int by = blockIdx.y;
  const int tid = threadIdx.x;
  const int wv = tid >> 6, ln = tid & 63;
  const int srow = ln >> 2;                              // 0..15
  const int scol = ((ln & 3) ^ ((srow >> 1) & 3)) * 8;   // swizzled K-slot

  const unsigned short* aSrc0 = A + (size_t)(m0 + wv * 32 + srow) * DM + scol;
  const unsigned short* aSrc1 = aSrc0 + (size_t)16 * DM;
  const unsigned short* bSrc0 = Bw + (size_t)(n0 + wv * 32 + srow) * DM + scol;
  const unsigned short* bSrc1 = bSrc0 + (size_t)16 * DM;
  unsigned short* aDst0 = &As[(wv * 32) * 32];
  unsigned short* aDst1 = &As[(wv * 32 + 16) * 32];
  unsigned short* bDst0 = &Bs[(wv * 32) * 32];
  unsigned short* bDst1 = &Bs[(wv * 32 + 16) * 32];

  const int quad = ln >> 4, l15 = ln & 15;
  const int slot = (quad ^ ((l15 >> 1) & 3)) * 8;        // read-side swizzle
  const int wr = (wv >> 1) * 64;                         // wave M offset
  const int wc = (wv & 1) * 64;                          // wave N offset

  f32x4 acc[4][4];
#pragma unroll
  for (int i = 0; i < 4; ++i)
#pragma unroll
    for (int j = 0; j < 4; ++j) {
      acc[i][j][0] = 0.f; acc[i][j][1] = 0.f; acc[i][j][2] = 0.f; acc[i][j][3] = 0.f;
    }

  for (int kt = 0; kt < 24; ++kt) {
    const int ko = kt * 32;
    gl_lds16(aSrc0 + ko, aDst0);
    gl_lds16(aSrc1 + ko, aDst1);
    gl_lds16(bSrc0 + ko, bDst0);
    gl_lds16(bSrc1 + ko, bDst1);
    __syncthreads();

    bf16x8 af[4], bfv[4];
#pragma unroll
    for (int i = 0; i < 4; ++i) {
      af[i]  = *(const bf16x8*)(As + (wr + i * 16 + l15) * 32 + slot);
      bfv[i] = *(const bf16x8*)(Bs + (wc + i * 16 + l15) * 32 + slot);
    }
#pragma unroll
    for (int mi = 0; mi < 4; ++mi)
#pragma unroll
      for (int ni = 0; ni < 4; ++ni)
        acc[mi][ni] = __builtin_amdgcn_mfma_f32_16x16x32_bf16(af[mi], bfv[ni], acc[mi][ni], 0, 0, 0);
    __syncthreads();
  }

  // ---- Epilogue part 1: non-temporal score stores (don't thrash W out of L3).
  // C/D layout: col = l15 (+ni*16), row = quad*4 + r (+mi*16).
#pragma unroll
  for (int mi = 0; mi < 4; ++mi) {
#pragma unroll
    for (int r = 0; r < 4; ++r) {
      const int row = m0 + wr + mi * 16 + quad * 4 + r;
      float* cp = C + (size_t)row * VOC + (n0 + wc + l15);
#pragma unroll
      for (int ni = 0; ni < 4; ++ni)
        __builtin_nontemporal_store(acc[mi][ni][r], cp + ni * 16);
    }
  }

  // ---- Epilogue part 2: per-row (max, sumexp) over this block's 128 cols.
  // Wave covers 64 rows x 64 cols. Reduce over ni in-lane, then over the 16
  // lanes of each quad group (shfl_xor 1,2,4,8 stays inside the group).
  float* pmL = (float*)As;   // [2][128] row max, reuse LDS
  float* psL = (float*)Bs;   // [2][128] row sumexp
  float rm[4][4], rs[4][4];
#pragma unroll
  for (int mi = 0; mi < 4; ++mi) {
#pragma unroll
    for (int r = 0; r < 4; ++r) {
      float m = fmaxf(fmaxf(acc[mi][0][r], acc[mi][1][r]),
                      fmaxf(acc[mi][2][r], acc[mi][3][r]));
#pragma unroll
      for (int off = 1; off < 16; off <<= 1) m = fmaxf(m, __shfl_xor(m, off));
      float s = __expf(acc[mi][0][r] - m) + __expf(acc[mi][1][r] - m) +
                __expf(acc[mi][2][r] - m) + __expf(acc[mi][3][r] - m);
#pragma unroll
      for (int off = 1; off < 16; off <<= 1) s += __shfl_xor(s, off);
      rm[mi][r] = m; rs[mi][r] = s;
    }
  }
  __syncthreads();   // LDS tiles no longer needed
  if (l15 == 0) {
#pragma unroll
    for (int mi = 0; mi < 4; ++mi)
#pragma unroll
      for (int r = 0; r < 4; ++r) {
        int row = wr + mi * 16 + quad * 4 + r;
        pmL[(wv & 1) * 128 + row] = rm[mi][r];
        psL[(wv & 1) * 128 + row] = rs[mi][r];
      }
  }
  __syncthreads();
  if (tid < 128) {
    float ma = pmL[tid], mb = pmL[128 + tid];
    float nm = fmaxf(ma, mb);
    float S = psL[tid] * __expf(ma - nm) + psL[128 + tid] * __expf(mb - nm);
    Pm[(size_t)by * NTOK + m0 + tid] = nm;     // coalesced: [by][token]
    Ps[(size_t)by * NTOK + m0 + tid] = S;
  }
}

// ---------------- combine 251 partials per token ----------------
__global__ void __launch_bounds__(256) loss_finalize_kernel(const float* __restrict__ Pm,
                                                            const float* __restrict__ Ps,
                                                            const float* __restrict__ scores,
                                                            const int* __restrict__ labels,
                                                            float* __restrict__ nll) {
  const int tok = blockIdx.x;
  float m = -1e30f, s = 0.f;
  for (int j = threadIdx.x; j < NBY; j += 256) {
    float m2 = Pm[(size_t)j * NTOK + tok], s2 = Ps[(size_t)j * NTOK + tok];
    float nm = fmaxf(m, m2);
    s = s * __expf(m - nm) + s2 * __expf(m2 - nm);
    m = nm;
  }
  for (int off = 32; off; off >>= 1) {
    float m2 = __shfl_down(m, off), s2 = __shfl_down(s, off);
    float nm = fmaxf(m, m2);
    s = s * __expf(m - nm) + s2 * __expf(m2 - nm);
    m = nm;
  }
  __shared__ float ms[4], sh[4];
  int wv = threadIdx.x >> 6, ln = threadIdx.x & 63;
  if (ln == 0) { ms[wv] = m; sh[wv] = s; }
  __syncthreads();
  if (threadIdx.x == 0) {
    float M = ms[0], S = sh[0];
    for (int i = 1; i < 4; ++i) {
      float nm = fmaxf(M, ms[i]);
      S = S * __expf(M - nm) + sh[i] * __expf(ms[i] - nm);
      M = nm;
    }
    int lab = labels[tok];
    float v = 0.f;
    if (lab != IGN) v = (M + logf(S)) - scores[(size_t)tok * VOC + lab];
    nll[tok] = v;
  }
}

__global__ void __launch_bounds__(256) reduce_kernel(const float* __restrict__ nll,
                                                     const int* __restrict__ labels,
                                                     float* __restrict__ out) {
  float s = 0.f, c = 0.f;
  for (int i = threadIdx.x; i < NTOK; i += 256) {
    s += nll[i];
    c += (labels[i] != IGN) ? 1.0f : 0.0f;
  }
  for (int off = 32; off; off >>= 1) { s += __shfl_down(s, off); c += __shfl_down(c, off); }
  __shared__ float rs[4], rc[4];
  int wv = threadIdx.x >> 6, ln = threadIdx.x & 63;
  if (ln == 0) { rs[wv] = s; rc[wv] = c; }
  __syncthreads();
  if (threadIdx.x == 0) {
    float S = rs[0] + rs[1] + rs[2] + rs[3];
    float Cc = rc[0] + rc[1] + rc[2] + rc[3];
    out[0] = S / fmaxf(Cc, 1.0f);
  }
}

extern "C" void kernel_launch(void* const* d_in, const int* in_sizes, int n_in,
                              void* d_out, int out_size, void* d_ws, size_t ws_size,
                              hipStream_t stream) {
  const float* hs     = (const float*)d_in[0];  // [4,512,768] f32
  const int*   labels = (const int*)d_in[1];    // [4,512] i32
  const float* lnw    = (const float*)d_in[2];  // [768] f32
  const float* W      = (const float*)d_in[3];  // [32128,768] f32

  float* out    = (float*)d_out;
  float* scores = out + 1;                      // [2048,32128] f32

  char* ws = (char*)d_ws;
  unsigned short* Wb = (unsigned short*)ws;                 ws += (size_t)VOC * DM * 2;   // 49.3 MB
  unsigned short* Hb = (unsigned short*)ws;                 ws += (size_t)NTOK * DM * 2;  // 3.1 MB
  float* Pm          = (float*)ws;                          ws += (size_t)NBY * NTOK * 4; // 2.06 MB
  float* Ps          = (float*)ws;                          ws += (size_t)NBY * NTOK * 4; // 2.06 MB
  float* nll         = (float*)ws;

  cvt_w_kernel<<<(VOC * DM / 4) / 256, 256, 0, stream>>>(W, Wb);
  rmsnorm_kernel<<<NTOK, 256, 0, stream>>>(hs, lnw, Hb);
  gemm_kernel<<<dim3(NTOK / 128, VOC / 128), 256, 0, stream>>>(Hb, Wb, scores, Pm, Ps);
  loss_finalize_kernel<<<NTOK, 256, 0, stream>>>(Pm, Ps, scores, labels, nll);
  reduce_kernel<<<1, 256, 0, stream>>>(nll, labels, out);
}